// Round 1
// 308.264 us; speedup vs baseline: 1.0724x; 1.0724x over previous
//
#include <hip/hip_runtime.h>
#include <hip/hip_fp16.h>
#include <stdint.h>

#define TILE 128
#define BK 32
#define LDST 40   // 32 + 8 pad: 80B row stride keeps 16B alignment, <=2-way bank alias

typedef __attribute__((ext_vector_type(8))) short short8;
typedef __attribute__((ext_vector_type(8))) unsigned short ushort8;
typedef __attribute__((ext_vector_type(4))) float f32x4;

static __device__ __forceinline__ unsigned short f2bf(float f) {
    union { float f; uint32_t u; } v; v.f = f;
    uint32_t u = v.u;
    u += 0x7fffu + ((u >> 16) & 1u);   // RNE
    return (unsigned short)(u >> 16);
}

// ---------------- W transpose+convert: Wt[n][k] bf16 from W[k][n] fp32 ----------------
__global__ __launch_bounds__(256)
void wt_kernel(const float* __restrict__ W, unsigned short* __restrict__ Wt)
{
    __shared__ float s[32][33];
    const int tx = threadIdx.x;          // 0..31
    const int ty = threadIdx.y;          // 0..7
    const int kBase = blockIdx.x * 32;
    const int nBase = blockIdx.y * 32;
    #pragma unroll
    for (int j = 0; j < 4; ++j)
        s[ty + 8 * j][tx] = W[(size_t)(kBase + ty + 8 * j) * 512 + nBase + tx];
    __syncthreads();
    #pragma unroll
    for (int j = 0; j < 4; ++j)
        Wt[(size_t)(nBase + ty + 8 * j) * 512 + kBase + tx] = f2bf(s[tx][ty + 8 * j]);
}

// ---------------- xp = x @ W + b  (M=65536, K=512, N=512) ----------------
// A from fp32 X (convert on stage), B from pre-transposed bf16 Wt[n][k].
// F16OUT path writes xp TRANSPOSED: xpT[b][r][t] fp16 so the scan reads contiguous t.
template <bool F16OUT>
__global__ __launch_bounds__(256, 4)
void gemm_bias_kernel(const float* __restrict__ X, const unsigned short* __restrict__ Wt,
                      const float* __restrict__ bias,
                      float* __restrict__ out32, __half* __restrict__ xpT)
{
    __shared__ unsigned short As[TILE * LDST];
    __shared__ unsigned short Bs[TILE * LDST];

    const int tid = threadIdx.x;

    // XCD-chunked tile remap: lin%8 -> XCD (round-robin dispatch); each XCD gets
    // 64 consecutive m-tiles x 4 n-tiles so blocks sharing an X stripe share an L2.
    const int lin = blockIdx.x;          // 0..2047
    const int xcd = lin & 7;
    const int idx = lin >> 3;            // 0..255
    const int rowBase = (xcd * 64 + (idx >> 2)) * TILE;
    const int colBase = (idx & 3) * TILE;

    const int wave  = tid >> 6;
    const int lane  = tid & 63;
    const int m16   = lane & 15;
    const int quad  = lane >> 4;
    const int waveM = wave & 1;
    const int waveN = wave >> 1;

    f32x4 acc[4][4] = {};

    const int srow = tid >> 2;   // 0..63
    const int sc4  = tid & 3;    // 0..3 (k-chunk of 8)

    for (int kt = 0; kt < 512; kt += BK) {
        // ---- stage A: 128 x 32, [m][k], convert fp32->bf16, ushort8 writes ----
        #pragma unroll
        for (int p = 0; p < 2; ++p) {
            int r = p * 64 + srow;
            const float* src = X + (size_t)(rowBase + r) * 512 + kt + sc4 * 8;
            float4 v0 = *(const float4*)(src);
            float4 v1 = *(const float4*)(src + 4);
            ushort8 us;
            us[0] = f2bf(v0.x); us[1] = f2bf(v0.y); us[2] = f2bf(v0.z); us[3] = f2bf(v0.w);
            us[4] = f2bf(v1.x); us[5] = f2bf(v1.y); us[6] = f2bf(v1.z); us[7] = f2bf(v1.w);
            *(ushort8*)(&As[r * LDST + sc4 * 8]) = us;
        }
        // ---- stage B: 128 x 32, [n][k] straight copy from Wt, ushort8 ----
        #pragma unroll
        for (int p = 0; p < 2; ++p) {
            int n = p * 64 + srow;
            ushort8 v = *(const ushort8*)(Wt + (size_t)(colBase + n) * 512 + kt + sc4 * 8);
            *(ushort8*)(&Bs[n * LDST + sc4 * 8]) = v;
        }
        __syncthreads();

        short8 a_frag[4], b_frag[4];
        #pragma unroll
        for (int mi = 0; mi < 4; ++mi)
            a_frag[mi] = *(const short8*)&As[(waveM * 64 + mi * 16 + m16) * LDST + quad * 8];
        #pragma unroll
        for (int ni = 0; ni < 4; ++ni)
            b_frag[ni] = *(const short8*)&Bs[(waveN * 64 + ni * 16 + m16) * LDST + quad * 8];

        #pragma unroll
        for (int mi = 0; mi < 4; ++mi)
            #pragma unroll
            for (int ni = 0; ni < 4; ++ni)
                acc[mi][ni] = __builtin_amdgcn_mfma_f32_16x16x32_bf16(
                    a_frag[mi], b_frag[ni], acc[mi][ni], 0, 0, 0);
        __syncthreads();
    }

    // ---- epilogue: + bias; C/D layout (m89): col=lane&15, row=quad*4+reg ----
    #pragma unroll
    for (int ni = 0; ni < 4; ++ni) {
        int col = colBase + waveN * 64 + ni * 16 + m16;
        float bv = bias[col];
        #pragma unroll
        for (int mi = 0; mi < 4; ++mi) {
            int row0 = rowBase + waveM * 64 + mi * 16 + quad * 4;
            if (F16OUT) {
                // rows = 4 consecutive t within one b -> one 8B store to xpT[b][col][t]
                int bb = row0 >> 10;
                int tt = row0 & 1023;
                union { __half h[4]; uint2 u; } pk;
                #pragma unroll
                for (int r = 0; r < 4; ++r)
                    pk.h[r] = __float2half_rn(acc[mi][ni][r] + bv);
                *(uint2*)(xpT + ((size_t)bb * 512 + col) * 1024 + tt) = pk.u;
            } else {
                #pragma unroll
                for (int r = 0; r < 4; ++r) {
                    float v = acc[mi][ni][r] + bv;
                    out32[(size_t)(row0 + r) * 512 + col] = v;
                }
            }
        }
    }
}

// ---------------- scan: h_t = relu(xp_t + u*h_{t-1}), h_0 = 1 ----------------
// xpT layout [B][R][T]: each lane streams a contiguous 2KB row via ushort8 (16B/lane),
// 128-deep double-buffered prefetch -> 16 x 1KB/wave outstanding.
#define SUNR 128

__global__ __launch_bounds__(64)
void scan_t_kernel(const __half* __restrict__ xpT, float* __restrict__ out,
                   const float* __restrict__ u)
{
    const int gid = blockIdx.x * 64 + threadIdx.x;  // 0..32767
    const int b = gid >> 9;
    const int r = gid & 511;
    const float ur = u[r];
    const unsigned short* p = (const unsigned short*)xpT + ((size_t)b * 512 + r) * 1024;
    float* po = out + (size_t)b * 1024 * 512 + r;

    float h = 1.0f;
    ushort8 cur[SUNR / 8], nxt[SUNR / 8];
    #pragma unroll
    for (int j = 0; j < SUNR / 8; ++j) cur[j] = *(const ushort8*)(p + j * 8);

    for (int t0 = 0; t0 < 1024; t0 += SUNR) {
        const bool more = (t0 + SUNR) < 1024;
        if (more) {
            #pragma unroll
            for (int j = 0; j < SUNR / 8; ++j)
                nxt[j] = *(const ushort8*)(p + t0 + SUNR + j * 8);
        }
        #pragma unroll
        for (int j = 0; j < SUNR / 8; ++j) {
            #pragma unroll
            for (int e = 0; e < 8; ++e) {
                float xv = __half2float(__ushort_as_half(cur[j][e]));
                h = fmaxf(fmaf(ur, h, xv), 0.0f);
                __builtin_nontemporal_store(h, po + (size_t)(t0 + j * 8 + e) * 512);
            }
        }
        #pragma unroll
        for (int j = 0; j < SUNR / 8; ++j) cur[j] = nxt[j];
    }
}

// fp32 in-place fallback (xp in out, [B,T,R] layout)
#define UNR 32
__global__ __launch_bounds__(64)
void scan_f32_kernel(float* __restrict__ out, const float* __restrict__ u)
{
    const int gid = blockIdx.x * 64 + threadIdx.x;
    const int b = gid >> 9;
    const int r = gid & 511;
    const float ur = u[r];
    float* p = out + (size_t)b * 1024 * 512 + r;

    float h = 1.0f;
    float cur[UNR], nxt[UNR];
    #pragma unroll
    for (int j = 0; j < UNR; ++j) cur[j] = p[(size_t)j * 512];

    for (int t0 = 0; t0 < 1024; t0 += UNR) {
        const bool more = (t0 + UNR) < 1024;
        const float* pn = p + (size_t)(t0 + UNR) * 512;
        if (more) {
            #pragma unroll
            for (int j = 0; j < UNR; ++j) nxt[j] = pn[(size_t)j * 512];
        }
        #pragma unroll
        for (int j = 0; j < UNR; ++j) {
            h = fmaxf(fmaf(ur, h, cur[j]), 0.0f);
            p[(size_t)(t0 + j) * 512] = h;
        }
        #pragma unroll
        for (int j = 0; j < UNR; ++j) cur[j] = nxt[j];
    }
}

extern "C" void kernel_launch(void* const* d_in, const int* in_sizes, int n_in,
                              void* d_out, int out_size, void* d_ws, size_t ws_size,
                              hipStream_t stream) {
    const float* x = (const float*)d_in[0];   // [64,1024,512]
    const float* W = (const float*)d_in[1];   // [512,512]
    const float* u = (const float*)d_in[2];   // [512]
    const float* b = (const float*)d_in[3];   // [512]
    float* out = (float*)d_out;               // [64,1024,512] fp32

    const size_t WT_BYTES = (size_t)512 * 512 * 2;              // 512 KB bf16 Wt
    const size_t XP_BYTES = (size_t)64 * 1024 * 512 * 2;        // 64 MB fp16 xpT
    unsigned short* Wt = (unsigned short*)d_ws;
    __half* xp16 = (__half*)((char*)d_ws + WT_BYTES);
    const bool f16path = ws_size >= WT_BYTES + XP_BYTES;        // deterministic -> graph-safe

    dim3 tgrid(16, 16), tblk(32, 8);
    wt_kernel<<<tgrid, tblk, 0, stream>>>(W, Wt);

    dim3 grid(2048);                          // 1D; XCD-chunked remap inside kernel
    if (f16path) {
        gemm_bias_kernel<true><<<grid, 256, 0, stream>>>(x, Wt, b, nullptr, xp16);
        scan_t_kernel<<<512, 64, 0, stream>>>(xp16, out, u);
    } else {
        gemm_bias_kernel<false><<<grid, 256, 0, stream>>>(x, Wt, b, out, nullptr);
        scan_f32_kernel<<<512, 64, 0, stream>>>(out, u);
    }
}

// Round 2
// 291.506 us; speedup vs baseline: 1.1341x; 1.0575x over previous
//
#include <hip/hip_runtime.h>
#include <hip/hip_fp16.h>
#include <stdint.h>

#define TILE 128
#define BK 32
#define LDST 40   // 32 + 8 pad: 80B row stride keeps 16B alignment, <=2-way bank alias

typedef __attribute__((ext_vector_type(8))) short short8;
typedef __attribute__((ext_vector_type(8))) unsigned short ushort8;
typedef __attribute__((ext_vector_type(4))) float f32x4;

static __device__ __forceinline__ unsigned short f2bf(float f) {
    union { float f; uint32_t u; } v; v.f = f;
    uint32_t u = v.u;
    u += 0x7fffu + ((u >> 16) & 1u);   // RNE
    return (unsigned short)(u >> 16);
}

// ---------------- W transpose+convert: Wt[n][k] bf16 from W[k][n] fp32 ----------------
__global__ __launch_bounds__(256)
void wt_kernel(const float* __restrict__ W, unsigned short* __restrict__ Wt)
{
    __shared__ float s[32][33];
    const int tx = threadIdx.x;          // 0..31
    const int ty = threadIdx.y;          // 0..7
    const int kBase = blockIdx.x * 32;
    const int nBase = blockIdx.y * 32;
    #pragma unroll
    for (int j = 0; j < 4; ++j)
        s[ty + 8 * j][tx] = W[(size_t)(kBase + ty + 8 * j) * 512 + nBase + tx];
    __syncthreads();
    #pragma unroll
    for (int j = 0; j < 4; ++j)
        Wt[(size_t)(nBase + ty + 8 * j) * 512 + kBase + tx] = f2bf(s[tx][ty + 8 * j]);
}

// ---------------- xp = x @ W + b  (M=65536, K=512, N=512) ----------------
// A from fp32 X (convert on stage), B from pre-transposed bf16 Wt[n][k].
// F16OUT path: MFMA operands SWAPPED (mfma(b,a) -> C^T in regs), so the fragment's
// lane axis is t -> 2B stores coalesce into 32B runs writing xpT[b][r][t].
template <bool F16OUT>
__global__ __launch_bounds__(256, 2)
void gemm_bias_kernel(const float* __restrict__ X, const unsigned short* __restrict__ Wt,
                      const float* __restrict__ bias,
                      float* __restrict__ out32, __half* __restrict__ xpT)
{
    __shared__ unsigned short As[TILE * LDST];
    __shared__ unsigned short Bs[TILE * LDST];

    const int tid = threadIdx.x;

    // XCD-chunked tile remap: lin%8 -> XCD (round-robin dispatch); each XCD gets
    // 64 consecutive m-tiles x 4 n-tiles so blocks sharing an X stripe share an L2.
    const int lin = blockIdx.x;          // 0..2047
    const int xcd = lin & 7;
    const int idx = lin >> 3;            // 0..255
    const int rowBase = (xcd * 64 + (idx >> 2)) * TILE;
    const int colBase = (idx & 3) * TILE;

    const int wave  = tid >> 6;
    const int lane  = tid & 63;
    const int m16   = lane & 15;
    const int quad  = lane >> 4;
    const int waveM = wave & 1;
    const int waveN = wave >> 1;

    f32x4 acc[4][4] = {};

    const int srow = tid >> 2;   // 0..63
    const int sc4  = tid & 3;    // 0..3 (k-chunk of 8)

    for (int kt = 0; kt < 512; kt += BK) {
        // ---- stage A: 128 x 32, [m][k], convert fp32->bf16, ushort8 writes ----
        #pragma unroll
        for (int p = 0; p < 2; ++p) {
            int r = p * 64 + srow;
            const float* src = X + (size_t)(rowBase + r) * 512 + kt + sc4 * 8;
            float4 v0 = *(const float4*)(src);
            float4 v1 = *(const float4*)(src + 4);
            ushort8 us;
            us[0] = f2bf(v0.x); us[1] = f2bf(v0.y); us[2] = f2bf(v0.z); us[3] = f2bf(v0.w);
            us[4] = f2bf(v1.x); us[5] = f2bf(v1.y); us[6] = f2bf(v1.z); us[7] = f2bf(v1.w);
            *(ushort8*)(&As[r * LDST + sc4 * 8]) = us;
        }
        // ---- stage B: 128 x 32, [n][k] straight copy from Wt, ushort8 ----
        #pragma unroll
        for (int p = 0; p < 2; ++p) {
            int n = p * 64 + srow;
            ushort8 v = *(const ushort8*)(Wt + (size_t)(colBase + n) * 512 + kt + sc4 * 8);
            *(ushort8*)(&Bs[n * LDST + sc4 * 8]) = v;
        }
        __syncthreads();

        short8 a_frag[4], b_frag[4];
        #pragma unroll
        for (int mi = 0; mi < 4; ++mi)
            a_frag[mi] = *(const short8*)&As[(waveM * 64 + mi * 16 + m16) * LDST + quad * 8];
        #pragma unroll
        for (int ni = 0; ni < 4; ++ni)
            b_frag[ni] = *(const short8*)&Bs[(waveN * 64 + ni * 16 + m16) * LDST + quad * 8];

        #pragma unroll
        for (int mi = 0; mi < 4; ++mi)
            #pragma unroll
            for (int ni = 0; ni < 4; ++ni) {
                if (F16OUT)   // swapped -> acc holds C^T fragment (lane axis = t)
                    acc[mi][ni] = __builtin_amdgcn_mfma_f32_16x16x32_bf16(
                        b_frag[ni], a_frag[mi], acc[mi][ni], 0, 0, 0);
                else
                    acc[mi][ni] = __builtin_amdgcn_mfma_f32_16x16x32_bf16(
                        a_frag[mi], b_frag[ni], acc[mi][ni], 0, 0, 0);
            }
        __syncthreads();
    }

    if (F16OUT) {
        // ---- epilogue (transposed frag): col(lane&15)=t, row(quad*4+reg)=r ----
        const int bb = rowBase >> 10;          // whole 128-row tile sits in one b
        #pragma unroll
        for (int ni = 0; ni < 4; ++ni) {
            int r0 = colBase + waveN * 64 + ni * 16 + quad * 4;
            float4 b4 = *(const float4*)&bias[r0];
            #pragma unroll
            for (int mi = 0; mi < 4; ++mi) {
                int tt = (rowBase + waveM * 64 + mi * 16 + m16) & 1023;
                #pragma unroll
                for (int r = 0; r < 4; ++r) {
                    float v = acc[mi][ni][r] + ((const float*)&b4)[r];
                    xpT[((size_t)bb * 512 + r0 + r) * 1024 + tt] = __float2half_rn(v);
                }
            }
        }
    } else {
        // ---- epilogue: + bias; C/D layout (m89): col=lane&15, row=quad*4+reg ----
        #pragma unroll
        for (int ni = 0; ni < 4; ++ni) {
            int col = colBase + waveN * 64 + ni * 16 + m16;
            float bv = bias[col];
            #pragma unroll
            for (int mi = 0; mi < 4; ++mi) {
                int row0 = rowBase + waveM * 64 + mi * 16 + quad * 4;
                #pragma unroll
                for (int r = 0; r < 4; ++r) {
                    float v = acc[mi][ni][r] + bv;
                    out32[(size_t)(row0 + r) * 512 + col] = v;
                }
            }
        }
    }
}

// ---------------- scan: h_t = relu(xp_t + u*h_{t-1}), h_0 = 1 ----------------
// xpT layout [B][R][T]: each lane streams a contiguous 2KB row via ushort8 (16B/lane),
// 128-deep double-buffered prefetch -> 16 x 1KB/wave outstanding.
#define SUNR 128

__global__ __launch_bounds__(64)
void scan_t_kernel(const __half* __restrict__ xpT, float* __restrict__ out,
                   const float* __restrict__ u)
{
    const int gid = blockIdx.x * 64 + threadIdx.x;  // 0..32767
    const int b = gid >> 9;
    const int r = gid & 511;
    const float ur = u[r];
    const unsigned short* p = (const unsigned short*)xpT + ((size_t)b * 512 + r) * 1024;
    float* po = out + (size_t)b * 1024 * 512 + r;

    float h = 1.0f;
    ushort8 cur[SUNR / 8], nxt[SUNR / 8];
    #pragma unroll
    for (int j = 0; j < SUNR / 8; ++j) cur[j] = *(const ushort8*)(p + j * 8);

    for (int t0 = 0; t0 < 1024; t0 += SUNR) {
        const bool more = (t0 + SUNR) < 1024;
        if (more) {
            #pragma unroll
            for (int j = 0; j < SUNR / 8; ++j)
                nxt[j] = *(const ushort8*)(p + t0 + SUNR + j * 8);
        }
        #pragma unroll
        for (int j = 0; j < SUNR / 8; ++j) {
            #pragma unroll
            for (int e = 0; e < 8; ++e) {
                float xv = __half2float(__ushort_as_half(cur[j][e]));
                h = fmaxf(fmaf(ur, h, xv), 0.0f);
                __builtin_nontemporal_store(h, po + (size_t)(t0 + j * 8 + e) * 512);
            }
        }
        #pragma unroll
        for (int j = 0; j < SUNR / 8; ++j) cur[j] = nxt[j];
    }
}

// fp32 in-place fallback (xp in out, [B,T,R] layout)
#define UNR 32
__global__ __launch_bounds__(64)
void scan_f32_kernel(float* __restrict__ out, const float* __restrict__ u)
{
    const int gid = blockIdx.x * 64 + threadIdx.x;
    const int b = gid >> 9;
    const int r = gid & 511;
    const float ur = u[r];
    float* p = out + (size_t)b * 1024 * 512 + r;

    float h = 1.0f;
    float cur[UNR], nxt[UNR];
    #pragma unroll
    for (int j = 0; j < UNR; ++j) cur[j] = p[(size_t)j * 512];

    for (int t0 = 0; t0 < 1024; t0 += UNR) {
        const bool more = (t0 + UNR) < 1024;
        const float* pn = p + (size_t)(t0 + UNR) * 512;
        if (more) {
            #pragma unroll
            for (int j = 0; j < UNR; ++j) nxt[j] = pn[(size_t)j * 512];
        }
        #pragma unroll
        for (int j = 0; j < UNR; ++j) {
            h = fmaxf(fmaf(ur, h, cur[j]), 0.0f);
            p[(size_t)(t0 + j) * 512] = h;
        }
        #pragma unroll
        for (int j = 0; j < UNR; ++j) cur[j] = nxt[j];
    }
}

extern "C" void kernel_launch(void* const* d_in, const int* in_sizes, int n_in,
                              void* d_out, int out_size, void* d_ws, size_t ws_size,
                              hipStream_t stream) {
    const float* x = (const float*)d_in[0];   // [64,1024,512]
    const float* W = (const float*)d_in[1];   // [512,512]
    const float* u = (const float*)d_in[2];   // [512]
    const float* b = (const float*)d_in[3];   // [512]
    float* out = (float*)d_out;               // [64,1024,512] fp32

    const size_t WT_BYTES = (size_t)512 * 512 * 2;              // 512 KB bf16 Wt
    const size_t XP_BYTES = (size_t)64 * 1024 * 512 * 2;        // 64 MB fp16 xpT
    unsigned short* Wt = (unsigned short*)d_ws;
    __half* xp16 = (__half*)((char*)d_ws + WT_BYTES);
    const bool f16path = ws_size >= WT_BYTES + XP_BYTES;        // deterministic -> graph-safe

    dim3 tgrid(16, 16), tblk(32, 8);
    wt_kernel<<<tgrid, tblk, 0, stream>>>(W, Wt);

    dim3 grid(2048);                          // 1D; XCD-chunked remap inside kernel
    if (f16path) {
        gemm_bias_kernel<true><<<grid, 256, 0, stream>>>(x, Wt, b, nullptr, xp16);
        scan_t_kernel<<<512, 64, 0, stream>>>(xp16, out, u);
    } else {
        gemm_bias_kernel<false><<<grid, 256, 0, stream>>>(x, Wt, b, out, nullptr);
        scan_f32_kernel<<<512, 64, 0, stream>>>(out, u);
    }
}